// Round 3
// baseline (279.847 us; speedup 1.0000x reference)
//
#include <hip/hip_runtime.h>
#include <hip/hip_bf16.h>

typedef __hip_bfloat16 bf16;
using bf16x8 = __attribute__((ext_vector_type(8))) short;
using f32x4  = __attribute__((ext_vector_type(4))) float;

#define C_DIM 512
#define L_DIM 2048
#define B_DIM 8

#define MFMA16(a, b, c) __builtin_amdgcn_mfma_f32_16x16x32_bf16(a, b, c, 0, 0, 0)

// ---- workspace layout (bytes) ----
// xT : [B][L][C] bf16, Wxb: bf16 weights [O][C]
// qT/kT: [B][L][64] bf16, vTT: [B][C][L] bf16, o1: [B][L][C] bf16
static const size_t OFF_XT  = 0;                      // 16 MB
static const size_t OFF_WQB = 16777216;
static const size_t OFF_WKB = 16842752;
static const size_t OFF_WVB = 16908288;
static const size_t OFF_WOB = 17432576;
static const size_t OFF_QT  = 17956864;
static const size_t OFF_KT  = 20054016;
static const size_t OFF_VT  = 22151168;
static const size_t OFF_O1  = 38928384;

// ---------------- K0a: weights fp32 -> bf16 ----------------
__global__ void k_wcvt(const float* __restrict__ Wq, const float* __restrict__ Wk,
                       const float* __restrict__ Wv, const float* __restrict__ Wo,
                       bf16* __restrict__ Wqb, bf16* __restrict__ Wkb,
                       bf16* __restrict__ Wvb, bf16* __restrict__ Wob) {
    int i = blockIdx.x * 256 + threadIdx.x;
    if (i < 32768)        Wqb[i]          = __float2bfloat16(Wq[i]);
    else if (i < 65536)   Wkb[i - 32768]  = __float2bfloat16(Wk[i - 32768]);
    else if (i < 327680)  Wvb[i - 65536]  = __float2bfloat16(Wv[i - 65536]);
    else                  Wob[i - 327680] = __float2bfloat16(Wo[i - 327680]);
}

// ---------------- K0b: transpose x [B][C][L] fp32 -> xT [B][L][C] bf16 ----------------
__global__ __launch_bounds__(256) void k_tr(const float* __restrict__ x,
                                            bf16* __restrict__ xT) {
    __shared__ float T[64][65];
    const int b = blockIdx.z;
    const int l0 = blockIdx.x * 64, c0 = blockIdx.y * 64;
    const int tx = threadIdx.x & 63, ty = threadIdx.x >> 6;

    const float* xp = x + ((size_t)b * C_DIM + c0) * L_DIM + l0;
#pragma unroll
    for (int i = 0; i < 16; ++i) {
        int c = i * 4 + ty;
        T[c][tx] = xp[(size_t)c * L_DIM + tx];
    }
    __syncthreads();
#pragma unroll
    for (int i = 0; i < 16; ++i) {
        int l = i * 4 + ty;
        xT[((size_t)b * L_DIM + l0 + l) * C_DIM + c0 + tx] = __float2bfloat16(T[tx][l]);
    }
}

// ---------------- K1: QKV projection via MFMA (reg-prefetched K-loop) ----------------
// NOTE: Q output is pre-scaled by 0.125 (= CQK^-0.5, exact pow2 -> bit-identical
// to scaling scores) so k_attn's inner loop drops the per-element scale mul.
__global__ __launch_bounds__(256, 2) void k_qkv(const bf16* __restrict__ xT,
                                                const bf16* __restrict__ Wqb, const float* __restrict__ bq,
                                                const bf16* __restrict__ Wkb, const float* __restrict__ bk,
                                                const bf16* __restrict__ Wvb, const float* __restrict__ bv,
                                                bf16* __restrict__ qT, bf16* __restrict__ kT,
                                                bf16* __restrict__ vTT) {
    const int b = blockIdx.z, y = blockIdx.y, bx = blockIdx.x;
    const int tid = threadIdx.x;
    const int w = tid >> 6, lane = tid & 63, quad = lane >> 4, l15 = lane & 15;
    const int wm = w >> 1, wn = w & 1;
    const size_t bL = (size_t)b * L_DIM;

    f32x4 acc[4][4];
#pragma unroll
    for (int i = 0; i < 4; ++i)
#pragma unroll
        for (int j = 0; j < 4; ++j) acc[i][j] = (f32x4){0.f, 0.f, 0.f, 0.f};

    const bf16* arow[4];
    const bf16* brow[4];
    if (y == 0) {
        const int mbase = bx * 128 + wm * 64;
        const bf16* Wb = wn ? Wkb : Wqb;
#pragma unroll
        for (int mi = 0; mi < 4; ++mi) arow[mi] = xT + (bL + mbase + mi * 16 + l15) * C_DIM;
#pragma unroll
        for (int ni = 0; ni < 4; ++ni) brow[ni] = Wb + (size_t)(ni * 16 + l15) * C_DIM;
    } else {
        const int cbase = (y - 1) * 128 + wm * 64;
        const int lbase = bx * 128 + wn * 64;
#pragma unroll
        for (int mi = 0; mi < 4; ++mi) arow[mi] = Wvb + (size_t)(cbase + mi * 16 + l15) * C_DIM;
#pragma unroll
        for (int ni = 0; ni < 4; ++ni) brow[ni] = xT + (bL + lbase + ni * 16 + l15) * C_DIM;
    }

    bf16x8 af[4], bfr[4], afn[4], bfn[4];
    {
        const int ko = quad * 8;
#pragma unroll
        for (int mi = 0; mi < 4; ++mi) af[mi] = *(const bf16x8*)(arow[mi] + ko);
#pragma unroll
        for (int ni = 0; ni < 4; ++ni) bfr[ni] = *(const bf16x8*)(brow[ni] + ko);
    }
    for (int kt = 0; kt < 16; ++kt) {
        if (kt < 15) {
            const int ko = (kt + 1) * 32 + quad * 8;
#pragma unroll
            for (int mi = 0; mi < 4; ++mi) afn[mi] = *(const bf16x8*)(arow[mi] + ko);
#pragma unroll
            for (int ni = 0; ni < 4; ++ni) bfn[ni] = *(const bf16x8*)(brow[ni] + ko);
        }
#pragma unroll
        for (int mi = 0; mi < 4; ++mi)
#pragma unroll
            for (int ni = 0; ni < 4; ++ni)
                acc[mi][ni] = MFMA16(af[mi], bfr[ni], acc[mi][ni]);
#pragma unroll
        for (int i = 0; i < 4; ++i) { af[i] = afn[i]; bfr[i] = bfn[i]; }
    }

    if (y == 0) {
        const int mbase = bx * 128 + wm * 64;
        const float* bias = wn ? bk : bq;
        bf16* dst = wn ? kT : qT;
        const float sc = wn ? 1.0f : 0.125f;
        float bb[4];
#pragma unroll
        for (int ni = 0; ni < 4; ++ni) bb[ni] = bias[ni * 16 + l15];
#pragma unroll
        for (int mi = 0; mi < 4; ++mi)
#pragma unroll
            for (int r = 0; r < 4; ++r) {
                int l = mbase + mi * 16 + quad * 4 + r;
#pragma unroll
                for (int ni = 0; ni < 4; ++ni)
                    dst[(bL + l) * 64 + ni * 16 + l15] = __float2bfloat16((acc[mi][ni][r] + bb[ni]) * sc);
            }
    } else {
        const int cbase = (y - 1) * 128 + wm * 64;
        const int lbase = bx * 128 + wn * 64;
#pragma unroll
        for (int mi = 0; mi < 4; ++mi)
#pragma unroll
            for (int r = 0; r < 4; ++r) {
                int c = cbase + mi * 16 + quad * 4 + r;
                float bb = bv[c];
#pragma unroll
                for (int ni = 0; ni < 4; ++ni)
                    vTT[((size_t)b * C_DIM + c) * L_DIM + lbase + ni * 16 + l15] =
                        __float2bfloat16(acc[mi][ni][r] + bb);
            }
    }
}

// ---------------- K2: single-pass MFMA attention ----------------
// Round-3 change (structural): occupancy was the binding constraint. Grid was
// 512 blocks = exactly 2 blocks/CU = 2 waves/SIMD; per-tile serial chain
// (score MFMA -> exp -> ds_write -> barrier -> ds_read -> PV) left the pipes
// ~85% idle and NOTHING could fill the bubbles (explains rounds 1-2 nulls).
// Now c-split 4: block = 64 q x 128 c, grid 1024 = 4 blocks/CU = 4 waves/SIMD,
// each SIMD hosting wave w of 4 DIFFERENT blocks (independent barriers ->
// chains de-phase and interleave). Score work duplicates 4x (small share);
// acc/VGPR shrink so 4 waves/SIMD fit. XCD pinning unchanged (b = bid&7).
// Wave w: score rows w*16..+15 (all k), PV slice: all 64 q x 32 c.
__global__ __launch_bounds__(256, 4) void k_attn(const bf16* __restrict__ qT,
                                                 const bf16* __restrict__ kT,
                                                 const bf16* __restrict__ vTT,
                                                 bf16* __restrict__ o1) {
    const int bid = blockIdx.x;
    const int b = bid & 7;
    const int cs = (bid >> 3) & 3;
    const int q0 = (bid >> 5) * 64;
    const int c0 = cs * 128;
    const int tid = threadIdx.x;
    const int w = tid >> 6, lane = tid & 63;
    const int quad = lane >> 4, l15 = lane & 15;

    __shared__ short P[2][64 * 40];     // pitch 40 shorts
    __shared__ float S_sh[64];

    const size_t bL = (size_t)b * L_DIM;

    // Q B-frags for wave's 16 rows (pre-scaled by 1/8)
    const bf16* qrow = qT + (bL + q0 + w * 16 + l15) * 64;
    bf16x8 qf0 = *(const bf16x8*)(qrow + quad * 8);
    bf16x8 qf1 = *(const bf16x8*)(qrow + 32 + quad * 8);

    f32x4 acc[4][2];
#pragma unroll
    for (int i = 0; i < 4; ++i)
#pragma unroll
        for (int j = 0; j < 2; ++j) acc[i][j] = (f32x4){0.f, 0.f, 0.f, 0.f};
    float ssum = 0.f;

    // V row pointers (B-frag: n=c via l15, k=l via quad); wave covers 32 c
    const bf16* vrow[2];
#pragma unroll
    for (int cg = 0; cg < 2; ++cg)
        vrow[cg] = vTT + ((size_t)b * C_DIM + c0 + w * 32 + cg * 16 + l15) * L_DIM + quad * 8;

    const bf16* kb = kT + bL * 64;

    bf16x8 kfA[2][2], kfB[2][2], vfA[2], vfB[2];
    // prologue: tile 0 into set A
#pragma unroll
    for (int kh = 0; kh < 2; ++kh)
#pragma unroll
        for (int h2 = 0; h2 < 2; ++h2)
            kfA[kh][h2] = *(const bf16x8*)(kb + (size_t)(kh * 16 + l15) * 64 + h2 * 32 + quad * 8);
#pragma unroll
    for (int cg = 0; cg < 2; ++cg) vfA[cg] = *(const bf16x8*)(vrow[cg]);

    // one tile: prefetch t+1 into (KN,VN); score+exp+stage from KC; raw barrier
    // (no vmem drain: prefetch loads stay in flight, counted vmcnt at use); PV from VC.
    auto tile = [&](int T, bf16x8 (&KC)[2][2], bf16x8 (&VC)[2],
                    bf16x8 (&KN)[2][2], bf16x8 (&VN)[2], short* Pb)
        __attribute__((always_inline)) -> void {
        const int k0 = T * 32;
        if (T < 63) {
#pragma unroll
            for (int kh = 0; kh < 2; ++kh)
#pragma unroll
                for (int h2 = 0; h2 < 2; ++h2)
                    KN[kh][h2] = *(const bf16x8*)(kb + (size_t)(k0 + 32 + kh * 16 + l15) * 64 + h2 * 32 + quad * 8);
#pragma unroll
            for (int cg = 0; cg < 2; ++cg) VN[cg] = *(const bf16x8*)(vrow[cg] + k0 + 32);
        }
#pragma unroll
        for (int kh = 0; kh < 2; ++kh) {
            f32x4 s = {0.f, 0.f, 0.f, 0.f};
            s = MFMA16(KC[kh][0], qf0, s);       // swapped: D[row=k, col=q]
            s = MFMA16(KC[kh][1], qf1, s);
            // s[r] = score(q = q0 + w*16 + l15, k = k0 + kh*16 + quad*4 + r)
            float p0 = __expf(fminf(s[0], 60.f) - 4.f);
            float p1 = __expf(fminf(s[1], 60.f) - 4.f);
            float p2 = __expf(fminf(s[2], 60.f) - 4.f);
            float p3 = __expf(fminf(s[3], 60.f) - 4.f);
            __hip_bfloat162 h01 = __float22bfloat162_rn(make_float2(p0, p1));
            __hip_bfloat162 h23 = __float22bfloat162_rn(make_float2(p2, p3));
            // S from the rounded values (normalization matches stored P)
            ssum += __bfloat162float(h01.x) + __bfloat162float(h01.y)
                  + __bfloat162float(h23.x) + __bfloat162float(h23.y);
            uint2 uu;
            uu.x = *reinterpret_cast<unsigned int*>(&h01);
            uu.y = *reinterpret_cast<unsigned int*>(&h23);
            *reinterpret_cast<uint2*>(&Pb[(w * 16 + l15) * 40 + kh * 16 + quad * 4]) = uu;
        }
        // P writes retired (LDS only) -> raw barrier. NO vmem drain.
        asm volatile("s_waitcnt lgkmcnt(0)" ::: "memory");
        __builtin_amdgcn_s_barrier();
        asm volatile("" ::: "memory");
        __builtin_amdgcn_sched_barrier(0);
        bf16x8 pf[4];
#pragma unroll
        for (int qg = 0; qg < 4; ++qg)
            pf[qg] = *(const bf16x8*)&Pb[(qg * 16 + l15) * 40 + quad * 8];
        __builtin_amdgcn_s_setprio(1);
#pragma unroll
        for (int qg = 0; qg < 4; ++qg)
#pragma unroll
            for (int cg = 0; cg < 2; ++cg)
                acc[qg][cg] = MFMA16(pf[qg], VC[cg], acc[qg][cg]);
        __builtin_amdgcn_s_setprio(0);
    };

    for (int t2 = 0; t2 < 32; ++t2) {
        tile(2 * t2,     kfA, vfA, kfB, vfB, P[0]);
        tile(2 * t2 + 1, kfB, vfB, kfA, vfA, P[1]);
    }

    // reduce S over the quad groups (lane bits 4,5): q = w*16 + l15 is lane-local
    ssum += __shfl_xor(ssum, 16, 64);
    ssum += __shfl_xor(ssum, 32, 64);
    if (lane < 16) S_sh[w * 16 + lane] = ssum;
    __syncthreads();
    if (tid < 64) S_sh[tid] = 1.f / S_sh[tid];
    __syncthreads();

    // epilogue: normalize + write o1[b][q][c]
#pragma unroll
    for (int qg = 0; qg < 4; ++qg) {
        float inv[4];
#pragma unroll
        for (int r = 0; r < 4; ++r) inv[r] = S_sh[qg * 16 + quad * 4 + r];
#pragma unroll
        for (int r = 0; r < 4; ++r) {
            const size_t base = (bL + q0 + qg * 16 + quad * 4 + r) * C_DIM + c0 + w * 32;
#pragma unroll
            for (int cg = 0; cg < 2; ++cg)
                o1[base + cg * 16 + l15] = __float2bfloat16(acc[qg][cg][r] * inv[r]);
        }
    }
}

// ---------------- K3: Wo GEMM + bias + residual via MFMA (reg-prefetched) ----------------
__global__ __launch_bounds__(256, 2) void k_out(const float* __restrict__ x,
                                                const bf16* __restrict__ Wob,
                                                const float* __restrict__ bo,
                                                const bf16* __restrict__ o1,
                                                float* __restrict__ out) {
    const int b = blockIdx.z;
    const int tid = threadIdx.x;
    const int w = tid >> 6, lane = tid & 63, quad = lane >> 4, l15 = lane & 15;
    const int wm = w >> 1, wn = w & 1;
    const int mbase = blockIdx.y * 128 + wm * 64;
    const int nbase = blockIdx.x * 128 + wn * 64;
    const size_t bL = (size_t)b * L_DIM;

    f32x4 acc[4][4];
#pragma unroll
    for (int i = 0; i < 4; ++i)
#pragma unroll
        for (int j = 0; j < 4; ++j) acc[i][j] = (f32x4){0.f, 0.f, 0.f, 0.f};

    const bf16* arow[4];
    const bf16* brow[4];
#pragma unroll
    for (int mi = 0; mi < 4; ++mi) arow[mi] = Wob + (size_t)(mbase + mi * 16 + l15) * C_DIM;
#pragma unroll
    for (int ni = 0; ni < 4; ++ni) brow[ni] = o1 + (bL + nbase + ni * 16 + l15) * C_DIM;

    bf16x8 af[4], bfr[4], afn[4], bfn[4];
    {
        const int ko = quad * 8;
#pragma unroll
        for (int mi = 0; mi < 4; ++mi) af[mi] = *(const bf16x8*)(arow[mi] + ko);
#pragma unroll
        for (int ni = 0; ni < 4; ++ni) bfr[ni] = *(const bf16x8*)(brow[ni] + ko);
    }
    for (int kt = 0; kt < 16; ++kt) {
        if (kt < 15) {
            const int ko = (kt + 1) * 32 + quad * 8;
#pragma unroll
            for (int mi = 0; mi < 4; ++mi) afn[mi] = *(const bf16x8*)(arow[mi] + ko);
#pragma unroll
            for (int ni = 0; ni < 4; ++ni) bfn[ni] = *(const bf16x8*)(brow[ni] + ko);
        }
#pragma unroll
        for (int mi = 0; mi < 4; ++mi)
#pragma unroll
            for (int ni = 0; ni < 4; ++ni)
                acc[mi][ni] = MFMA16(af[mi], bfr[ni], acc[mi][ni]);
#pragma unroll
        for (int i = 0; i < 4; ++i) { af[i] = afn[i]; bfr[i] = bfn[i]; }
    }

#pragma unroll
    for (int mi = 0; mi < 4; ++mi)
#pragma unroll
        for (int r = 0; r < 4; ++r) {
            int row = mbase + mi * 16 + quad * 4 + r;
            float bb = bo[row];
            size_t base = ((size_t)b * C_DIM + row) * L_DIM + nbase;
#pragma unroll
            for (int ni = 0; ni < 4; ++ni) {
                size_t idx = base + ni * 16 + l15;
                out[idx] = acc[mi][ni][r] + bb + x[idx];
            }
        }
}

extern "C" void kernel_launch(void* const* d_in, const int* in_sizes, int n_in,
                              void* d_out, int out_size, void* d_ws, size_t ws_size,
                              hipStream_t stream) {
    const float* x  = (const float*)d_in[0];
    const float* Wq = (const float*)d_in[1];
    const float* bq = (const float*)d_in[2];
    const float* Wk = (const float*)d_in[3];
    const float* bk = (const float*)d_in[4];
    const float* Wv = (const float*)d_in[5];
    const float* bv = (const float*)d_in[6];
    const float* Wo = (const float*)d_in[7];
    const float* bo = (const float*)d_in[8];

    char* wsb = (char*)d_ws;
    bf16* xT  = (bf16*)(wsb + OFF_XT);
    bf16* Wqb = (bf16*)(wsb + OFF_WQB);
    bf16* Wkb = (bf16*)(wsb + OFF_WKB);
    bf16* Wvb = (bf16*)(wsb + OFF_WVB);
    bf16* Wob = (bf16*)(wsb + OFF_WOB);
    bf16* qT  = (bf16*)(wsb + OFF_QT);
    bf16* kT  = (bf16*)(wsb + OFF_KT);
    bf16* vTT = (bf16*)(wsb + OFF_VT);
    bf16* o1  = (bf16*)(wsb + OFF_O1);
    float* out = (float*)d_out;

    k_wcvt<<<dim3(2304), 256, 0, stream>>>(Wq, Wk, Wv, Wo, Wqb, Wkb, Wvb, Wob);
    k_tr<<<dim3(L_DIM / 64, C_DIM / 64, B_DIM), 256, 0, stream>>>(x, xT);
    k_qkv<<<dim3(16, 5, B_DIM), 256, 0, stream>>>(xT, Wqb, bq, Wkb, bk, Wvb, bv, qT, kT, vTT);
    k_attn<<<dim3(1024), 256, 0, stream>>>(qT, kT, vTT, o1);
    k_out<<<dim3(16, 4, B_DIM), 256, 0, stream>>>(x, Wob, bo, o1, out);
}

// Round 4
// 177.688 us; speedup vs baseline: 1.5749x; 1.5749x over previous
//
#include <hip/hip_runtime.h>
#include <hip/hip_bf16.h>

typedef __hip_bfloat16 bf16;
using bf16x8 = __attribute__((ext_vector_type(8))) short;
using f32x4  = __attribute__((ext_vector_type(4))) float;

#define C_DIM 512
#define L_DIM 2048
#define B_DIM 8

#define MFMA16(a, b, c) __builtin_amdgcn_mfma_f32_16x16x32_bf16(a, b, c, 0, 0, 0)

// ---- workspace layout (bytes) ----
static const size_t OFF_XT  = 0;                      // 16 MB
static const size_t OFF_WQB = 16777216;
static const size_t OFF_WKB = 16842752;
static const size_t OFF_WVB = 16908288;
static const size_t OFF_WOB = 17432576;
static const size_t OFF_QT  = 17956864;
static const size_t OFF_KT  = 20054016;
static const size_t OFF_VT  = 22151168;
static const size_t OFF_O1  = 38928384;

// ---------------- K0a: weights fp32 -> bf16 ----------------
__global__ void k_wcvt(const float* __restrict__ Wq, const float* __restrict__ Wk,
                       const float* __restrict__ Wv, const float* __restrict__ Wo,
                       bf16* __restrict__ Wqb, bf16* __restrict__ Wkb,
                       bf16* __restrict__ Wvb, bf16* __restrict__ Wob) {
    int i = blockIdx.x * 256 + threadIdx.x;
    if (i < 32768)        Wqb[i]          = __float2bfloat16(Wq[i]);
    else if (i < 65536)   Wkb[i - 32768]  = __float2bfloat16(Wk[i - 32768]);
    else if (i < 327680)  Wvb[i - 65536]  = __float2bfloat16(Wv[i - 65536]);
    else                  Wob[i - 327680] = __float2bfloat16(Wo[i - 327680]);
}

// ---------------- K0b: transpose x [B][C][L] fp32 -> xT [B][L][C] bf16 ----------------
__global__ __launch_bounds__(256) void k_tr(const float* __restrict__ x,
                                            bf16* __restrict__ xT) {
    __shared__ float T[64][65];
    const int b = blockIdx.z;
    const int l0 = blockIdx.x * 64, c0 = blockIdx.y * 64;
    const int tx = threadIdx.x & 63, ty = threadIdx.x >> 6;

    const float* xp = x + ((size_t)b * C_DIM + c0) * L_DIM + l0;
#pragma unroll
    for (int i = 0; i < 16; ++i) {
        int c = i * 4 + ty;
        T[c][tx] = xp[(size_t)c * L_DIM + tx];
    }
    __syncthreads();
#pragma unroll
    for (int i = 0; i < 16; ++i) {
        int l = i * 4 + ty;
        xT[((size_t)b * L_DIM + l0 + l) * C_DIM + c0 + tx] = __float2bfloat16(T[tx][l]);
    }
}

// ---------------- K1: QKV projection via MFMA (reg-prefetched K-loop) ----------------
// Q output pre-scaled by 0.125 (exact pow2, bit-identical to scaling scores).
__global__ __launch_bounds__(256, 2) void k_qkv(const bf16* __restrict__ xT,
                                                const bf16* __restrict__ Wqb, const float* __restrict__ bq,
                                                const bf16* __restrict__ Wkb, const float* __restrict__ bk,
                                                const bf16* __restrict__ Wvb, const float* __restrict__ bv,
                                                bf16* __restrict__ qT, bf16* __restrict__ kT,
                                                bf16* __restrict__ vTT) {
    const int b = blockIdx.z, y = blockIdx.y, bx = blockIdx.x;
    const int tid = threadIdx.x;
    const int w = tid >> 6, lane = tid & 63, quad = lane >> 4, l15 = lane & 15;
    const int wm = w >> 1, wn = w & 1;
    const size_t bL = (size_t)b * L_DIM;

    f32x4 acc[4][4];
#pragma unroll
    for (int i = 0; i < 4; ++i)
#pragma unroll
        for (int j = 0; j < 4; ++j) acc[i][j] = (f32x4){0.f, 0.f, 0.f, 0.f};

    const bf16* arow[4];
    const bf16* brow[4];
    if (y == 0) {
        const int mbase = bx * 128 + wm * 64;
        const bf16* Wb = wn ? Wkb : Wqb;
#pragma unroll
        for (int mi = 0; mi < 4; ++mi) arow[mi] = xT + (bL + mbase + mi * 16 + l15) * C_DIM;
#pragma unroll
        for (int ni = 0; ni < 4; ++ni) brow[ni] = Wb + (size_t)(ni * 16 + l15) * C_DIM;
    } else {
        const int cbase = (y - 1) * 128 + wm * 64;
        const int lbase = bx * 128 + wn * 64;
#pragma unroll
        for (int mi = 0; mi < 4; ++mi) arow[mi] = Wvb + (size_t)(cbase + mi * 16 + l15) * C_DIM;
#pragma unroll
        for (int ni = 0; ni < 4; ++ni) brow[ni] = xT + (bL + lbase + ni * 16 + l15) * C_DIM;
    }

    bf16x8 af[4], bfr[4], afn[4], bfn[4];
    {
        const int ko = quad * 8;
#pragma unroll
        for (int mi = 0; mi < 4; ++mi) af[mi] = *(const bf16x8*)(arow[mi] + ko);
#pragma unroll
        for (int ni = 0; ni < 4; ++ni) bfr[ni] = *(const bf16x8*)(brow[ni] + ko);
    }
    for (int kt = 0; kt < 16; ++kt) {
        if (kt < 15) {
            const int ko = (kt + 1) * 32 + quad * 8;
#pragma unroll
            for (int mi = 0; mi < 4; ++mi) afn[mi] = *(const bf16x8*)(arow[mi] + ko);
#pragma unroll
            for (int ni = 0; ni < 4; ++ni) bfn[ni] = *(const bf16x8*)(brow[ni] + ko);
        }
#pragma unroll
        for (int mi = 0; mi < 4; ++mi)
#pragma unroll
            for (int ni = 0; ni < 4; ++ni)
                acc[mi][ni] = MFMA16(af[mi], bfr[ni], acc[mi][ni]);
#pragma unroll
        for (int i = 0; i < 4; ++i) { af[i] = afn[i]; bfr[i] = bfn[i]; }
    }

    if (y == 0) {
        const int mbase = bx * 128 + wm * 64;
        const float* bias = wn ? bk : bq;
        bf16* dst = wn ? kT : qT;
        const float sc = wn ? 1.0f : 0.125f;
        float bb[4];
#pragma unroll
        for (int ni = 0; ni < 4; ++ni) bb[ni] = bias[ni * 16 + l15];
#pragma unroll
        for (int mi = 0; mi < 4; ++mi)
#pragma unroll
            for (int r = 0; r < 4; ++r) {
                int l = mbase + mi * 16 + quad * 4 + r;
#pragma unroll
                for (int ni = 0; ni < 4; ++ni)
                    dst[(bL + l) * 64 + ni * 16 + l15] = __float2bfloat16((acc[mi][ni][r] + bb[ni]) * sc);
            }
    } else {
        const int cbase = (y - 1) * 128 + wm * 64;
        const int lbase = bx * 128 + wn * 64;
#pragma unroll
        for (int mi = 0; mi < 4; ++mi)
#pragma unroll
            for (int r = 0; r < 4; ++r) {
                int c = cbase + mi * 16 + quad * 4 + r;
                float bb = bv[c];
#pragma unroll
                for (int ni = 0; ni < 4; ++ni)
                    vTT[((size_t)b * C_DIM + c) * L_DIM + lbase + ni * 16 + l15] =
                        __float2bfloat16(acc[mi][ni][r] + bb);
            }
    }
}

// ---------------- K2: L2-traffic-minimized MFMA attention ----------------
// Round-4 restructure. Model (fits r0-r3): k_attn was L2-BW-bound; traffic
// = B*L^2*C*2 / Q_block. Old Q_block=64 -> 1.07 GB @ ~8.4 TB/s = 128 us;
// r3 doubled K traffic -> 1.45x slower. Fix is volume, not scheduling:
//  - Q_block = 256 (8 waves x 32 q-rows, 512 thr), c-split 4, grid 256
//    (1 block/CU, b = bid&7 XCD-pinned). V global 537->134 MB, K staged.
//  - K (4KB) and V (8KB) tiles staged to LDS per 32-k step via
//    global_load_lds w16, TRIPLE-buffered, counted vmcnt(2) (never 0
//    mid-loop), ONE barrier per tile.
//  - P stays in registers: each wave's PV covers its own 32 q, so the
//    QK->PV relayout is intra-wave: 4 ds_bpermute + 2 selects per 16-q
//    subtile (k-pair (2j,2j+1) of target quad comes from source quad
//    2*(quad&1)+(j>>1), register h01/h23 of kh=quad>>1). No P-LDS, no
//    second barrier.
//  - XOR swizzles (pre-swizzled GLOBAL source, linear DMA dest; same XOR
//    on read): K slot^=(k&7), V part^=((c>>1)&3) -> all ds_read_b128
//    <=2-way conflicts (free).
// Unnormalized P~ = exp(min(s,60)-4) bf16, S from rounded values, deferred
// 1/S in epilogue (unchanged numerics).
__global__ __launch_bounds__(512, 2) void k_attn(const bf16* __restrict__ qT,
                                                 const bf16* __restrict__ kT,
                                                 const bf16* __restrict__ vTT,
                                                 bf16* __restrict__ o1) {
    const int bid = blockIdx.x;
    const int b  = bid & 7;
    const int qt = (bid >> 3) & 7;
    const int cs = bid >> 6;                 // 0..3
    const int q0 = qt * 256;
    const int c0 = cs * 128;
    const int tid = threadIdx.x;
    const int w = tid >> 6, lane = tid & 63;
    const int quad = lane >> 4, l15 = lane & 15;

    // V: 3 bufs x 8KB @0 ; K: 3 bufs x 4KB @24576
    __shared__ __align__(16) char lds[36864];

    const size_t bL = (size_t)b * L_DIM;
    const bf16* kb = kT + bL * 64;

    // Q fragments: two 16-row subtiles (q = q0 + w*32 + u*16 + l15), pre-scaled
    bf16x8 qf[2][2];
#pragma unroll
    for (int u = 0; u < 2; ++u) {
        const bf16* qrow = qT + (bL + q0 + w * 32 + u * 16 + l15) * 64;
        qf[u][0] = *(const bf16x8*)(qrow + quad * 8);
        qf[u][1] = *(const bf16x8*)(qrow + 32 + quad * 8);
    }

    f32x4 acc[2][8];
#pragma unroll
    for (int u = 0; u < 2; ++u)
#pragma unroll
        for (int cg = 0; cg < 8; ++cg) acc[u][cg] = (f32x4){0.f, 0.f, 0.f, 0.f};
    float ssum[2] = {0.f, 0.f};

    // cooperative stage of tile kt into buffer bufi (2 loads per thread)
    auto stage = [&](int kt, int bufi) __attribute__((always_inline)) {
        {   // V tile: 128 c-rows x 64B, layout [c][4x16B], part pre-swizzled
            const int cl = tid >> 2, ps = tid & 3;
            const int pg = ps ^ ((cl >> 1) & 3);
            const bf16* src = vTT + ((size_t)b * C_DIM + c0 + cl) * L_DIM + kt * 32 + pg * 8;
            __builtin_amdgcn_global_load_lds(
                (const __attribute__((address_space(1))) void*)src,
                (__attribute__((address_space(3))) void*)(lds + bufi * 8192 + w * 1024),
                16, 0, 0);
        }
        {   // K tile: 32 k-rows x 128B, layout [k][8x16B]; waves 4-7 write a
            // duplicate of the same bytes (uniform 2 loads/thread for vmcnt)
            const int i = tid & 255, k = i >> 3, sl = i & 7;
            const int sg = sl ^ (k & 7);
            const bf16* src = kb + (size_t)(kt * 32 + k) * 64 + sg * 8;
            __builtin_amdgcn_global_load_lds(
                (const __attribute__((address_space(1))) void*)src,
                (__attribute__((address_space(3))) void*)(lds + 24576 + bufi * 4096 + (w & 3) * 1024),
                16, 0, 0);
        }
    };

    auto body = [&](int t, int bc, int bs) __attribute__((always_inline)) {
        // stage(t) complete (2 loads of stage t+1 may stay outstanding)
        if (t == 63) asm volatile("s_waitcnt vmcnt(0)" ::: "memory");
        else         asm volatile("s_waitcnt vmcnt(2)" ::: "memory");
        __builtin_amdgcn_s_barrier();           // all waves' stage(t) visible;
        __builtin_amdgcn_sched_barrier(0);      // nothing hoists above this
        if (t < 62) stage(t + 2, bs);           // issue next-next tile now

        char* Kb = lds + 24576 + bc * 4096;
        char* Vb = lds + bc * 8192;

        bf16x8 kf[2][2];
#pragma unroll
        for (int kh = 0; kh < 2; ++kh)
#pragma unroll
            for (int h2 = 0; h2 < 2; ++h2)
                kf[kh][h2] = *(const bf16x8*)(Kb + (kh * 16 + l15) * 128 +
                                              (((h2 * 4 + quad) ^ (l15 & 7)) << 4));

        unsigned hh[2][2][2];   // [u][kh][pair01/pair23]
#pragma unroll
        for (int u = 0; u < 2; ++u)
#pragma unroll
            for (int kh = 0; kh < 2; ++kh) {
                f32x4 s = {0.f, 0.f, 0.f, 0.f};
                s = MFMA16(kf[kh][0], qf[u][0], s);    // D[row=k, col=q]
                s = MFMA16(kf[kh][1], qf[u][1], s);
                float p0 = __expf(fminf(s[0], 60.f) - 4.f);
                float p1 = __expf(fminf(s[1], 60.f) - 4.f);
                float p2 = __expf(fminf(s[2], 60.f) - 4.f);
                float p3 = __expf(fminf(s[3], 60.f) - 4.f);
                __hip_bfloat162 h01 = __float22bfloat162_rn(make_float2(p0, p1));
                __hip_bfloat162 h23 = __float22bfloat162_rn(make_float2(p2, p3));
                ssum[u] += __bfloat162float(h01.x) + __bfloat162float(h01.y)
                         + __bfloat162float(h23.x) + __bfloat162float(h23.y);
                hh[u][kh][0] = *reinterpret_cast<unsigned*>(&h01);
                hh[u][kh][1] = *reinterpret_cast<unsigned*>(&h23);
            }

        // intra-wave P relayout to PV A-frag: lane needs k = quad*8..+7
        const int srcA = ((quad & 1) * 32 + l15) * 4;
        bf16x8 pa[2];
#pragma unroll
        for (int u = 0; u < 2; ++u) {
            int sel01 = (quad < 2) ? (int)hh[u][0][0] : (int)hh[u][1][0];
            int sel23 = (quad < 2) ? (int)hh[u][0][1] : (int)hh[u][1][1];
            int a0 = __builtin_amdgcn_ds_bpermute(srcA,      sel01);
            int a1 = __builtin_amdgcn_ds_bpermute(srcA,      sel23);
            int a2 = __builtin_amdgcn_ds_bpermute(srcA + 64, sel01);
            int a3 = __builtin_amdgcn_ds_bpermute(srcA + 64, sel23);
            int4 pi = make_int4(a0, a1, a2, a3);
            pa[u] = *reinterpret_cast<bf16x8*>(&pi);
        }

        // PV: each V B-frag feeds both q-subtiles
#pragma unroll
        for (int cg = 0; cg < 8; ++cg) {
            const int cl = cg * 16 + l15;
            bf16x8 vB = *(const bf16x8*)(Vb + cl * 64 + ((quad ^ ((cl >> 1) & 3)) << 4));
            acc[0][cg] = MFMA16(pa[0], vB, acc[0][cg]);
            acc[1][cg] = MFMA16(pa[1], vB, acc[1][cg]);
        }
    };

    stage(0, 0);
    stage(1, 1);
    for (int t = 0; t < 63; t += 3) {
        body(t,     0, 2);
        body(t + 1, 1, 0);
        body(t + 2, 2, 1);
    }
    body(63, 0, 0);   // tail: vmcnt(0), no stage

    // epilogue: reduce S over quads (q = l15 lane-local), normalize, store
#pragma unroll
    for (int u = 0; u < 2; ++u) {
        ssum[u] += __shfl_xor(ssum[u], 16, 64);
        ssum[u] += __shfl_xor(ssum[u], 32, 64);
        float sinv = 1.f / ssum[u];
#pragma unroll
        for (int r = 0; r < 4; ++r) {
            float iv = __shfl(sinv, quad * 4 + r, 64);
            const size_t base = (bL + q0 + w * 32 + u * 16 + quad * 4 + r) * C_DIM + c0;
#pragma unroll
            for (int cg = 0; cg < 8; ++cg)
                o1[base + cg * 16 + l15] = __float2bfloat16(acc[u][cg][r] * iv);
        }
    }
}

// ---------------- K3: Wo GEMM + bias + residual via MFMA (reg-prefetched) ----------------
__global__ __launch_bounds__(256, 2) void k_out(const float* __restrict__ x,
                                                const bf16* __restrict__ Wob,
                                                const float* __restrict__ bo,
                                                const bf16* __restrict__ o1,
                                                float* __restrict__ out) {
    const int b = blockIdx.z;
    const int tid = threadIdx.x;
    const int w = tid >> 6, lane = tid & 63, quad = lane >> 4, l15 = lane & 15;
    const int wm = w >> 1, wn = w & 1;
    const int mbase = blockIdx.y * 128 + wm * 64;
    const int nbase = blockIdx.x * 128 + wn * 64;
    const size_t bL = (size_t)b * L_DIM;

    f32x4 acc[4][4];
#pragma unroll
    for (int i = 0; i < 4; ++i)
#pragma unroll
        for (int j = 0; j < 4; ++j) acc[i][j] = (f32x4){0.f, 0.f, 0.f, 0.f};

    const bf16* arow[4];
    const bf16* brow[4];
#pragma unroll
    for (int mi = 0; mi < 4; ++mi) arow[mi] = Wob + (size_t)(mbase + mi * 16 + l15) * C_DIM;
#pragma unroll
    for (int ni = 0; ni < 4; ++ni) brow[ni] = o1 + (bL + nbase + ni * 16 + l15) * C_DIM;

    bf16x8 af[4], bfr[4], afn[4], bfn[4];
    {
        const int ko = quad * 8;
#pragma unroll
        for (int mi = 0; mi < 4; ++mi) af[mi] = *(const bf16x8*)(arow[mi] + ko);
#pragma unroll
        for (int ni = 0; ni < 4; ++ni) bfr[ni] = *(const bf16x8*)(brow[ni] + ko);
    }
    for (int kt = 0; kt < 16; ++kt) {
        if (kt < 15) {
            const int ko = (kt + 1) * 32 + quad * 8;
#pragma unroll
            for (int mi = 0; mi < 4; ++mi) afn[mi] = *(const bf16x8*)(arow[mi] + ko);
#pragma unroll
            for (int ni = 0; ni < 4; ++ni) bfn[ni] = *(const bf16x8*)(brow[ni] + ko);
        }
#pragma unroll
        for (int mi = 0; mi < 4; ++mi)
#pragma unroll
            for (int ni = 0; ni < 4; ++ni)
                acc[mi][ni] = MFMA16(af[mi], bfr[ni], acc[mi][ni]);
#pragma unroll
        for (int i = 0; i < 4; ++i) { af[i] = afn[i]; bfr[i] = bfn[i]; }
    }

#pragma unroll
    for (int mi = 0; mi < 4; ++mi)
#pragma unroll
        for (int r = 0; r < 4; ++r) {
            int row = mbase + mi * 16 + quad * 4 + r;
            float bb = bo[row];
            size_t base = ((size_t)b * C_DIM + row) * L_DIM + nbase;
#pragma unroll
            for (int ni = 0; ni < 4; ++ni) {
                size_t idx = base + ni * 16 + l15;
                out[idx] = acc[mi][ni][r] + bb + x[idx];
            }
        }
}

extern "C" void kernel_launch(void* const* d_in, const int* in_sizes, int n_in,
                              void* d_out, int out_size, void* d_ws, size_t ws_size,
                              hipStream_t stream) {
    const float* x  = (const float*)d_in[0];
    const float* Wq = (const float*)d_in[1];
    const float* bq = (const float*)d_in[2];
    const float* Wk = (const float*)d_in[3];
    const float* bk = (const float*)d_in[4];
    const float* Wv = (const float*)d_in[5];
    const float* bv = (const float*)d_in[6];
    const float* Wo = (const float*)d_in[7];
    const float* bo = (const float*)d_in[8];

    char* wsb = (char*)d_ws;
    bf16* xT  = (bf16*)(wsb + OFF_XT);
    bf16* Wqb = (bf16*)(wsb + OFF_WQB);
    bf16* Wkb = (bf16*)(wsb + OFF_WKB);
    bf16* Wvb = (bf16*)(wsb + OFF_WVB);
    bf16* Wob = (bf16*)(wsb + OFF_WOB);
    bf16* qT  = (bf16*)(wsb + OFF_QT);
    bf16* kT  = (bf16*)(wsb + OFF_KT);
    bf16* vTT = (bf16*)(wsb + OFF_VT);
    bf16* o1  = (bf16*)(wsb + OFF_O1);
    float* out = (float*)d_out;

    k_wcvt<<<dim3(2304), 256, 0, stream>>>(Wq, Wk, Wv, Wo, Wqb, Wkb, Wvb, Wob);
    k_tr<<<dim3(L_DIM / 64, C_DIM / 64, B_DIM), 256, 0, stream>>>(x, xT);
    k_qkv<<<dim3(16, 5, B_DIM), 256, 0, stream>>>(xT, Wqb, bq, Wkb, bk, Wvb, bv, qT, kT, vTT);
    k_attn<<<dim3(256), 512, 0, stream>>>(qT, kT, vTT, o1);
    k_out<<<dim3(16, 4, B_DIM), 256, 0, stream>>>(x, Wob, bo, o1, out);
}

// Round 5
// 177.652 us; speedup vs baseline: 1.5753x; 1.0002x over previous
//
#include <hip/hip_runtime.h>
#include <hip/hip_bf16.h>

typedef __hip_bfloat16 bf16;
using bf16x8 = __attribute__((ext_vector_type(8))) short;
using f32x4  = __attribute__((ext_vector_type(4))) float;

#define C_DIM 512
#define L_DIM 2048
#define B_DIM 8

#define MFMA16(a, b, c) __builtin_amdgcn_mfma_f32_16x16x32_bf16(a, b, c, 0, 0, 0)

// ---- workspace layout (bytes) ----
static const size_t OFF_XT  = 0;                      // 16 MB
static const size_t OFF_WQB = 16777216;
static const size_t OFF_WKB = 16842752;
static const size_t OFF_WVB = 16908288;
static const size_t OFF_WOB = 17432576;
static const size_t OFF_QT  = 17956864;
static const size_t OFF_KT  = 20054016;
static const size_t OFF_VT  = 22151168;
static const size_t OFF_O1  = 38928384;

// ---------------- K0a: weights fp32 -> bf16 ----------------
__global__ void k_wcvt(const float* __restrict__ Wq, const float* __restrict__ Wk,
                       const float* __restrict__ Wv, const float* __restrict__ Wo,
                       bf16* __restrict__ Wqb, bf16* __restrict__ Wkb,
                       bf16* __restrict__ Wvb, bf16* __restrict__ Wob) {
    int i = blockIdx.x * 256 + threadIdx.x;
    if (i < 32768)        Wqb[i]          = __float2bfloat16(Wq[i]);
    else if (i < 65536)   Wkb[i - 32768]  = __float2bfloat16(Wk[i - 32768]);
    else if (i < 327680)  Wvb[i - 65536]  = __float2bfloat16(Wv[i - 65536]);
    else                  Wob[i - 327680] = __float2bfloat16(Wo[i - 327680]);
}

// ---------------- K0b: transpose x [B][C][L] fp32 -> xT [B][L][C] bf16 ----------------
__global__ __launch_bounds__(256) void k_tr(const float* __restrict__ x,
                                            bf16* __restrict__ xT) {
    __shared__ float T[64][65];
    const int b = blockIdx.z;
    const int l0 = blockIdx.x * 64, c0 = blockIdx.y * 64;
    const int tx = threadIdx.x & 63, ty = threadIdx.x >> 6;

    const float* xp = x + ((size_t)b * C_DIM + c0) * L_DIM + l0;
#pragma unroll
    for (int i = 0; i < 16; ++i) {
        int c = i * 4 + ty;
        T[c][tx] = xp[(size_t)c * L_DIM + tx];
    }
    __syncthreads();
#pragma unroll
    for (int i = 0; i < 16; ++i) {
        int l = i * 4 + ty;
        xT[((size_t)b * L_DIM + l0 + l) * C_DIM + c0 + tx] = __float2bfloat16(T[tx][l]);
    }
}

// ---------------- K1: QKV projection via MFMA (reg-prefetched K-loop) ----------------
// Q output pre-scaled by 0.125 (exact pow2, bit-identical to scaling scores).
__global__ __launch_bounds__(256, 2) void k_qkv(const bf16* __restrict__ xT,
                                                const bf16* __restrict__ Wqb, const float* __restrict__ bq,
                                                const bf16* __restrict__ Wkb, const float* __restrict__ bk,
                                                const bf16* __restrict__ Wvb, const float* __restrict__ bv,
                                                bf16* __restrict__ qT, bf16* __restrict__ kT,
                                                bf16* __restrict__ vTT) {
    const int b = blockIdx.z, y = blockIdx.y, bx = blockIdx.x;
    const int tid = threadIdx.x;
    const int w = tid >> 6, lane = tid & 63, quad = lane >> 4, l15 = lane & 15;
    const int wm = w >> 1, wn = w & 1;
    const size_t bL = (size_t)b * L_DIM;

    f32x4 acc[4][4];
#pragma unroll
    for (int i = 0; i < 4; ++i)
#pragma unroll
        for (int j = 0; j < 4; ++j) acc[i][j] = (f32x4){0.f, 0.f, 0.f, 0.f};

    const bf16* arow[4];
    const bf16* brow[4];
    if (y == 0) {
        const int mbase = bx * 128 + wm * 64;
        const bf16* Wb = wn ? Wkb : Wqb;
#pragma unroll
        for (int mi = 0; mi < 4; ++mi) arow[mi] = xT + (bL + mbase + mi * 16 + l15) * C_DIM;
#pragma unroll
        for (int ni = 0; ni < 4; ++ni) brow[ni] = Wb + (size_t)(ni * 16 + l15) * C_DIM;
    } else {
        const int cbase = (y - 1) * 128 + wm * 64;
        const int lbase = bx * 128 + wn * 64;
#pragma unroll
        for (int mi = 0; mi < 4; ++mi) arow[mi] = Wvb + (size_t)(cbase + mi * 16 + l15) * C_DIM;
#pragma unroll
        for (int ni = 0; ni < 4; ++ni) brow[ni] = xT + (bL + lbase + ni * 16 + l15) * C_DIM;
    }

    bf16x8 af[4], bfr[4], afn[4], bfn[4];
    {
        const int ko = quad * 8;
#pragma unroll
        for (int mi = 0; mi < 4; ++mi) af[mi] = *(const bf16x8*)(arow[mi] + ko);
#pragma unroll
        for (int ni = 0; ni < 4; ++ni) bfr[ni] = *(const bf16x8*)(brow[ni] + ko);
    }
    for (int kt = 0; kt < 16; ++kt) {
        if (kt < 15) {
            const int ko = (kt + 1) * 32 + quad * 8;
#pragma unroll
            for (int mi = 0; mi < 4; ++mi) afn[mi] = *(const bf16x8*)(arow[mi] + ko);
#pragma unroll
            for (int ni = 0; ni < 4; ++ni) bfn[ni] = *(const bf16x8*)(brow[ni] + ko);
        }
#pragma unroll
        for (int mi = 0; mi < 4; ++mi)
#pragma unroll
            for (int ni = 0; ni < 4; ++ni)
                acc[mi][ni] = MFMA16(af[mi], bfr[ni], acc[mi][ni]);
#pragma unroll
        for (int i = 0; i < 4; ++i) { af[i] = afn[i]; bfr[i] = bfn[i]; }
    }

    if (y == 0) {
        const int mbase = bx * 128 + wm * 64;
        const float* bias = wn ? bk : bq;
        bf16* dst = wn ? kT : qT;
        const float sc = wn ? 1.0f : 0.125f;
        float bb[4];
#pragma unroll
        for (int ni = 0; ni < 4; ++ni) bb[ni] = bias[ni * 16 + l15];
#pragma unroll
        for (int mi = 0; mi < 4; ++mi)
#pragma unroll
            for (int r = 0; r < 4; ++r) {
                int l = mbase + mi * 16 + quad * 4 + r;
#pragma unroll
                for (int ni = 0; ni < 4; ++ni)
                    dst[(bL + l) * 64 + ni * 16 + l15] = __float2bfloat16((acc[mi][ni][r] + bb[ni]) * sc);
            }
    } else {
        const int cbase = (y - 1) * 128 + wm * 64;
        const int lbase = bx * 128 + wn * 64;
#pragma unroll
        for (int mi = 0; mi < 4; ++mi)
#pragma unroll
            for (int r = 0; r < 4; ++r) {
                int c = cbase + mi * 16 + quad * 4 + r;
                float bb = bv[c];
#pragma unroll
                for (int ni = 0; ni < 4; ++ni)
                    vTT[((size_t)b * C_DIM + c) * L_DIM + lbase + ni * 16 + l15] =
                        __float2bfloat16(acc[mi][ni][r] + bb);
            }
    }
}

// ---------------- K2: L2-traffic-minimized MFMA attention, score-ahead pipelined ----------------
// Round-5 change: r4 counters (Mfma 25%, VALU 50%, occ 20%) show the limit is the
// intra-wave serial chain {kf read -> score MFMA -> exp -> bpermute -> PV MFMA}
// with only 2 waves/SIMD to cross-fill (~50% bubble: 3037 cy/tile vs ~1500 pipe
// floor). Fix: software-pipeline SCORE ONE TILE AHEAD of PV within each wave --
// possible since r4 made the P relayout intra-wave (no score->PV barrier).
// Per iteration i: {pre-read V(i-1) B-frags (pre-barrier; valid since barrier
// i-1)} -> vmcnt(2)+barrier -> stage(i+2) -> score(i)+exp(i)+relayout -> paN,
// PV(i-1) MFMAs from paC -- score(i) and PV(i-1) are INDEPENDENT chains the
// scheduler interleaves. 4 LDS buffers (stage(i+2) never lands on V(i-1));
// paA/paB ping-pong via x2 unroll (static reg indexing). ssum from unrounded
// floats (saves cvts; ~2^-10 normalization shift). Staging/swizzles identical
// to the r4-verified code. Geometry unchanged: Q_block=256, c-split 4, grid 256.
__global__ __launch_bounds__(512, 2) void k_attn(const bf16* __restrict__ qT,
                                                 const bf16* __restrict__ kT,
                                                 const bf16* __restrict__ vTT,
                                                 bf16* __restrict__ o1) {
    const int bid = blockIdx.x;
    const int b  = bid & 7;
    const int qt = (bid >> 3) & 7;
    const int cs = bid >> 6;                 // 0..3
    const int q0 = qt * 256;
    const int c0 = cs * 128;
    const int tid = threadIdx.x;
    const int w = tid >> 6, lane = tid & 63;
    const int quad = lane >> 4, l15 = lane & 15;

    // V: 4 bufs x 8KB @0 ; K: 4 bufs x 4KB @32768
    __shared__ __align__(16) char lds[49152];

    const size_t bL = (size_t)b * L_DIM;
    const bf16* kb = kT + bL * 64;

    // Q fragments: two 16-row subtiles (q = q0 + w*32 + u*16 + l15), pre-scaled
    bf16x8 qf[2][2];
#pragma unroll
    for (int u = 0; u < 2; ++u) {
        const bf16* qrow = qT + (bL + q0 + w * 32 + u * 16 + l15) * 64;
        qf[u][0] = *(const bf16x8*)(qrow + quad * 8);
        qf[u][1] = *(const bf16x8*)(qrow + 32 + quad * 8);
    }

    f32x4 acc[2][8];
#pragma unroll
    for (int u = 0; u < 2; ++u)
#pragma unroll
        for (int cg = 0; cg < 8; ++cg) acc[u][cg] = (f32x4){0.f, 0.f, 0.f, 0.f};
    float ssum[2] = {0.f, 0.f};

    // hoisted per-lane offsets
    const int vbase = l15 * 64 + ((quad ^ ((l15 >> 1) & 3)) << 4);   // + cg*1024
    const int srcA  = ((quad & 1) * 32 + l15) * 4;

    // cooperative stage of tile kt into buffer bufi (2 loads per thread) -- r4-verified
    auto stage = [&](int kt, int bufi) __attribute__((always_inline)) {
        {   // V tile: 128 c-rows x 64B, layout [c][4x16B], part pre-swizzled
            const int cl = tid >> 2, ps = tid & 3;
            const int pg = ps ^ ((cl >> 1) & 3);
            const bf16* src = vTT + ((size_t)b * C_DIM + c0 + cl) * L_DIM + kt * 32 + pg * 8;
            __builtin_amdgcn_global_load_lds(
                (const __attribute__((address_space(1))) void*)src,
                (__attribute__((address_space(3))) void*)(lds + bufi * 8192 + w * 1024),
                16, 0, 0);
        }
        {   // K tile: 32 k-rows x 128B, layout [k][8x16B]; waves 4-7 duplicate
            const int i = tid & 255, k = i >> 3, sl = i & 7;
            const int sg = sl ^ (k & 7);
            const bf16* src = kb + (size_t)(kt * 32 + k) * 64 + sg * 8;
            __builtin_amdgcn_global_load_lds(
                (const __attribute__((address_space(1))) void*)src,
                (__attribute__((address_space(3))) void*)(lds + 32768 + bufi * 4096 + (w & 3) * 1024),
                16, 0, 0);
        }
    };

    bf16x8 paA[2], paB[2];

    // one pipeline step: PV(i-1) from paC/V(i-1), score(i) -> paN, stage(i+2)
    auto step = [&](int i, bf16x8 (&paC)[2], bf16x8 (&paN)[2],
                    bool doPV, bool doStage, int vm) __attribute__((always_inline)) {
        // pre-read V(i-1) B-frags BEFORE the sync (buffer valid since barrier i-1;
        // next write to it is stage(i+3), issued after barrier i+1)
        bf16x8 vBr[8];
        if (doPV) {
            char* Vb = lds + ((i - 1) & 3) * 8192;
#pragma unroll
            for (int cg = 0; cg < 8; ++cg)
                vBr[cg] = *(const bf16x8*)(Vb + vbase + cg * 1024);
        }
        if (vm == 0) asm volatile("s_waitcnt vmcnt(0)" ::: "memory");
        else         asm volatile("s_waitcnt vmcnt(2)" ::: "memory");
        __builtin_amdgcn_s_barrier();
        __builtin_amdgcn_sched_barrier(0);
        if (doStage) stage(i + 2, (i + 2) & 3);

        // score(i): kf reads + MFMA + exp + pack
        char* Kb = lds + 32768 + (i & 3) * 4096;
        bf16x8 kf[2][2];
#pragma unroll
        for (int kh = 0; kh < 2; ++kh)
#pragma unroll
            for (int h2 = 0; h2 < 2; ++h2)
                kf[kh][h2] = *(const bf16x8*)(Kb + (kh * 16 + l15) * 128 +
                                              (((h2 * 4 + quad) ^ (l15 & 7)) << 4));

        unsigned hh[2][2][2];   // [u][kh][pair01/pair23]
#pragma unroll
        for (int u = 0; u < 2; ++u)
#pragma unroll
            for (int kh = 0; kh < 2; ++kh) {
                f32x4 s = {0.f, 0.f, 0.f, 0.f};
                s = MFMA16(kf[kh][0], qf[u][0], s);    // D[row=k, col=q]
                s = MFMA16(kf[kh][1], qf[u][1], s);
                float p0 = __expf(fminf(s[0], 60.f) - 4.f);
                float p1 = __expf(fminf(s[1], 60.f) - 4.f);
                float p2 = __expf(fminf(s[2], 60.f) - 4.f);
                float p3 = __expf(fminf(s[3], 60.f) - 4.f);
                ssum[u] += (p0 + p1) + (p2 + p3);      // unrounded sum
                __hip_bfloat162 h01 = __float22bfloat162_rn(make_float2(p0, p1));
                __hip_bfloat162 h23 = __float22bfloat162_rn(make_float2(p2, p3));
                hh[u][kh][0] = *reinterpret_cast<unsigned*>(&h01);
                hh[u][kh][1] = *reinterpret_cast<unsigned*>(&h23);
            }

        // PV(i-1): independent of the score/exp chain -> scheduler interleaves
        if (doPV) {
#pragma unroll
            for (int cg = 0; cg < 8; ++cg) {
                acc[0][cg] = MFMA16(paC[0], vBr[cg], acc[0][cg]);
                acc[1][cg] = MFMA16(paC[1], vBr[cg], acc[1][cg]);
            }
        }

        // relayout(i) -> paN (needed next step)
#pragma unroll
        for (int u = 0; u < 2; ++u) {
            int sel01 = (quad < 2) ? (int)hh[u][0][0] : (int)hh[u][1][0];
            int sel23 = (quad < 2) ? (int)hh[u][0][1] : (int)hh[u][1][1];
            int a0 = __builtin_amdgcn_ds_bpermute(srcA,      sel01);
            int a1 = __builtin_amdgcn_ds_bpermute(srcA,      sel23);
            int a2 = __builtin_amdgcn_ds_bpermute(srcA + 64, sel01);
            int a3 = __builtin_amdgcn_ds_bpermute(srcA + 64, sel23);
            int4 pi = make_int4(a0, a1, a2, a3);
            paN[u] = *reinterpret_cast<bf16x8*>(&pi);
        }
    };

    stage(0, 0);
    stage(1, 1);
    step(0, paA, paA, false, true, 2);                 // score(0)->paA, stage(2)
    for (int i = 1; i < 63; i += 2) {
        step(i,     paA, paB, true, true,        2);   // PV(i-1), score(i)->paB
        step(i + 1, paB, paA, true, (i + 1) <= 61, 2); // PV(i),   score(i+1)->paA
    }
    step(63, paA, paB, true, false, 0);                // PV(62), score(63)->paB

    // drain: PV(63) from buffer 3
    {
        char* Vb = lds + 3 * 8192;
#pragma unroll
        for (int cg = 0; cg < 8; ++cg) {
            bf16x8 vB = *(const bf16x8*)(Vb + vbase + cg * 1024);
            acc[0][cg] = MFMA16(paB[0], vB, acc[0][cg]);
            acc[1][cg] = MFMA16(paB[1], vB, acc[1][cg]);
        }
    }

    // epilogue: reduce S over quads (q = l15 lane-local), normalize, store
#pragma unroll
    for (int u = 0; u < 2; ++u) {
        ssum[u] += __shfl_xor(ssum[u], 16, 64);
        ssum[u] += __shfl_xor(ssum[u], 32, 64);
        float sinv = 1.f / ssum[u];
#pragma unroll
        for (int r = 0; r < 4; ++r) {
            float iv = __shfl(sinv, quad * 4 + r, 64);
            const size_t base = (bL + q0 + w * 32 + u * 16 + quad * 4 + r) * C_DIM + c0;
#pragma unroll
            for (int cg = 0; cg < 8; ++cg)
                o1[base + cg * 16 + l15] = __float2bfloat16(acc[u][cg][r] * iv);
        }
    }
}

// ---------------- K3: Wo GEMM + bias + residual via MFMA (reg-prefetched) ----------------
__global__ __launch_bounds__(256, 2) void k_out(const float* __restrict__ x,
                                                const bf16* __restrict__ Wob,
                                                const float* __restrict__ bo,
                                                const bf16* __restrict__ o1,
                                                float* __restrict__ out) {
    const int b = blockIdx.z;
    const int tid = threadIdx.x;
    const int w = tid >> 6, lane = tid & 63, quad = lane >> 4, l15 = lane & 15;
    const int wm = w >> 1, wn = w & 1;
    const int mbase = blockIdx.y * 128 + wm * 64;
    const int nbase = blockIdx.x * 128 + wn * 64;
    const size_t bL = (size_t)b * L_DIM;

    f32x4 acc[4][4];
#pragma unroll
    for (int i = 0; i < 4; ++i)
#pragma unroll
        for (int j = 0; j < 4; ++j) acc[i][j] = (f32x4){0.f, 0.f, 0.f, 0.f};

    const bf16* arow[4];
    const bf16* brow[4];
#pragma unroll
    for (int mi = 0; mi < 4; ++mi) arow[mi] = Wob + (size_t)(mbase + mi * 16 + l15) * C_DIM;
#pragma unroll
    for (int ni = 0; ni < 4; ++ni) brow[ni] = o1 + (bL + nbase + ni * 16 + l15) * C_DIM;

    bf16x8 af[4], bfr[4], afn[4], bfn[4];
    {
        const int ko = quad * 8;
#pragma unroll
        for (int mi = 0; mi < 4; ++mi) af[mi] = *(const bf16x8*)(arow[mi] + ko);
#pragma unroll
        for (int ni = 0; ni < 4; ++ni) bfr[ni] = *(const bf16x8*)(brow[ni] + ko);
    }
    for (int kt = 0; kt < 16; ++kt) {
        if (kt < 15) {
            const int ko = (kt + 1) * 32 + quad * 8;
#pragma unroll
            for (int mi = 0; mi < 4; ++mi) afn[mi] = *(const bf16x8*)(arow[mi] + ko);
#pragma unroll
            for (int ni = 0; ni < 4; ++ni) bfn[ni] = *(const bf16x8*)(brow[ni] + ko);
        }
#pragma unroll
        for (int mi = 0; mi < 4; ++mi)
#pragma unroll
            for (int ni = 0; ni < 4; ++ni)
                acc[mi][ni] = MFMA16(af[mi], bfr[ni], acc[mi][ni]);
#pragma unroll
        for (int i = 0; i < 4; ++i) { af[i] = afn[i]; bfr[i] = bfn[i]; }
    }

#pragma unroll
    for (int mi = 0; mi < 4; ++mi)
#pragma unroll
        for (int r = 0; r < 4; ++r) {
            int row = mbase + mi * 16 + quad * 4 + r;
            float bb = bo[row];
            size_t base = ((size_t)b * C_DIM + row) * L_DIM + nbase;
#pragma unroll
            for (int ni = 0; ni < 4; ++ni) {
                size_t idx = base + ni * 16 + l15;
                out[idx] = acc[mi][ni][r] + bb + x[idx];
            }
        }
}

extern "C" void kernel_launch(void* const* d_in, const int* in_sizes, int n_in,
                              void* d_out, int out_size, void* d_ws, size_t ws_size,
                              hipStream_t stream) {
    const float* x  = (const float*)d_in[0];
    const float* Wq = (const float*)d_in[1];
    const float* bq = (const float*)d_in[2];
    const float* Wk = (const float*)d_in[3];
    const float* bk = (const float*)d_in[4];
    const float* Wv = (const float*)d_in[5];
    const float* bv = (const float*)d_in[6];
    const float* Wo = (const float*)d_in[7];
    const float* bo = (const float*)d_in[8];

    char* wsb = (char*)d_ws;
    bf16* xT  = (bf16*)(wsb + OFF_XT);
    bf16* Wqb = (bf16*)(wsb + OFF_WQB);
    bf16* Wkb = (bf16*)(wsb + OFF_WKB);
    bf16* Wvb = (bf16*)(wsb + OFF_WVB);
    bf16* Wob = (bf16*)(wsb + OFF_WOB);
    bf16* qT  = (bf16*)(wsb + OFF_QT);
    bf16* kT  = (bf16*)(wsb + OFF_KT);
    bf16* vTT = (bf16*)(wsb + OFF_VT);
    bf16* o1  = (bf16*)(wsb + OFF_O1);
    float* out = (float*)d_out;

    k_wcvt<<<dim3(2304), 256, 0, stream>>>(Wq, Wk, Wv, Wo, Wqb, Wkb, Wvb, Wob);
    k_tr<<<dim3(L_DIM / 64, C_DIM / 64, B_DIM), 256, 0, stream>>>(x, xT);
    k_qkv<<<dim3(16, 5, B_DIM), 256, 0, stream>>>(xT, Wqb, bq, Wkb, bk, Wvb, bv, qT, kT, vTT);
    k_attn<<<dim3(256), 512, 0, stream>>>(qT, kT, vTT, o1);
    k_out<<<dim3(16, 4, B_DIM), 256, 0, stream>>>(x, Wob, bo, o1, out);
}